// Round 2
// 84.831 us; speedup vs baseline: 1.0574x; 1.0574x over previous
//
#include <hip/hip_runtime.h>
#include <hip/hip_fp16.h>
#include <math.h>

// u_dot_v + sigmoid, D=64.
// R2: f32 h (12.8 MB) -> fp16 table (6.4 MB) in d_ws; 8 lanes/edge gather
//     16 B each (one 128 B line per row), f32 dot, shfl reduce.   [89.7 us]
// R3: latency theory — dot kernel is bound by scattered L2/LLC hit latency
//     with only 2 in-flight gathers/thread. Process 4 edges per 8-lane
//     group: 2x int4 index loads (coalesced broadcast), then 8 independent
//     dwordx4 gathers in flight before any reduce (~3x MLP). Indices/out
//     use nontemporal hints to keep the fp16 table hot in per-XCD L2.
// R4: compile fix — nontemporal builtins need native vector types, not
//     HIP_vector_type. Use ext_vector_type typedefs for those accesses.

#define DOT_D 64

typedef int   v4i __attribute__((ext_vector_type(4)));
typedef float v4f __attribute__((ext_vector_type(4)));

__global__ __launch_bounds__(256) void f32_to_f16_kernel(
    const float* __restrict__ h, __half2* __restrict__ hh, int n4)
{
    int i = blockIdx.x * blockDim.x + threadIdx.x;
    if (i >= n4) return;
    float4 v = ((const float4*)h)[i];
    hh[2 * i]     = __floats2half2_rn(v.x, v.y);
    hh[2 * i + 1] = __floats2half2_rn(v.z, v.w);
}

// 4 edges per 8-lane group; 8 gathers in flight per thread.
__global__ __launch_bounds__(256) void dot_sigmoid_f16_mlp_kernel(
    const __half* __restrict__ h,
    const int* __restrict__ src,
    const int* __restrict__ dst,
    float* __restrict__ out,
    int E)
{
    int tid  = blockIdx.x * blockDim.x + threadIdx.x;
    int lane = tid & 7;     // 8 lanes per edge-group
    int g    = tid >> 3;    // group id: edges 4g .. 4g+3
    int eb   = g << 2;
    if (eb >= E) return;

    if (eb + 3 < E) {
        // Coalesced broadcast index loads: all 8 lanes read the same 16 B.
        v4i s4 = __builtin_nontemporal_load((const v4i*)(src + eb));
        v4i d4 = __builtin_nontemporal_load((const v4i*)(dst + eb));
        int ss[4] = { s4.x, s4.y, s4.z, s4.w };
        int dd[4] = { d4.x, d4.y, d4.z, d4.w };

        // Issue all 8 independent gathers (16 B/lane, one 128 B line/row).
        float4 ur[4], vr[4];
#pragma unroll
        for (int i = 0; i < 4; ++i) {
            ur[i] = ((const float4*)(h + (size_t)ss[i] * DOT_D))[lane];
            vr[i] = ((const float4*)(h + (size_t)dd[i] * DOT_D))[lane];
        }

        v4f res;
#pragma unroll
        for (int i = 0; i < 4; ++i) {
            const __half2* up = (const __half2*)&ur[i];
            const __half2* vp = (const __half2*)&vr[i];
            float p = 0.0f;
#pragma unroll
            for (int k = 0; k < 4; ++k) {
                float2 uf = __half22float2(up[k]);
                float2 vf = __half22float2(vp[k]);
                p = fmaf(uf.x, vf.x, p);
                p = fmaf(uf.y, vf.y, p);
            }
            p += __shfl_xor(p, 4);
            p += __shfl_xor(p, 2);
            p += __shfl_xor(p, 1);
            res[i] = 1.0f / (1.0f + __expf(-p));
        }

        if (lane == 0) {
            __builtin_nontemporal_store(res, (v4f*)(out + eb));
        }
    } else {
        // Tail: per-edge scalar path (E not divisible by 4).
        for (int i = 0; i < 4; ++i) {
            int e = eb + i;
            if (e >= E) break;
            int s = src[e];
            int d = dst[e];
            float4 ur = ((const float4*)(h + (size_t)s * DOT_D))[lane];
            float4 vr = ((const float4*)(h + (size_t)d * DOT_D))[lane];
            const __half2* up = (const __half2*)&ur;
            const __half2* vp = (const __half2*)&vr;
            float p = 0.0f;
#pragma unroll
            for (int k = 0; k < 4; ++k) {
                float2 uf = __half22float2(up[k]);
                float2 vf = __half22float2(vp[k]);
                p = fmaf(uf.x, vf.x, p);
                p = fmaf(uf.y, vf.y, p);
            }
            p += __shfl_xor(p, 4);
            p += __shfl_xor(p, 2);
            p += __shfl_xor(p, 1);
            if (lane == 0) out[e] = 1.0f / (1.0f + __expf(-p));
        }
    }
}

// f32 fallback (R1 kernel) if d_ws is too small for the fp16 table.
__global__ __launch_bounds__(256) void dot_sigmoid_f32_kernel(
    const float* __restrict__ h,
    const int* __restrict__ src,
    const int* __restrict__ dst,
    float* __restrict__ out,
    int E)
{
    int tid  = blockIdx.x * blockDim.x + threadIdx.x;
    int lane = tid & 15;
    int e    = tid >> 4;
    if (e >= E) return;

    int s = src[e];
    int d = dst[e];
    float4 u = ((const float4*)(h + (size_t)s * DOT_D))[lane];
    float4 v = ((const float4*)(h + (size_t)d * DOT_D))[lane];
    float p = u.x * v.x + u.y * v.y + u.z * v.z + u.w * v.w;
    p += __shfl_xor(p, 8);
    p += __shfl_xor(p, 4);
    p += __shfl_xor(p, 2);
    p += __shfl_xor(p, 1);
    if (lane == 0) out[e] = 1.0f / (1.0f + __expf(-p));
}

extern "C" void kernel_launch(void* const* d_in, const int* in_sizes, int n_in,
                              void* d_out, int out_size, void* d_ws, size_t ws_size,
                              hipStream_t stream) {
    const float* h   = (const float*)d_in[0];
    const int*   src = (const int*)d_in[1];
    const int*   dst = (const int*)d_in[2];
    float*       out = (float*)d_out;

    int ND = in_sizes[0];          // N * 64
    int E  = in_sizes[1];
    size_t f16_bytes = (size_t)ND * sizeof(__half);

    if (ws_size >= f16_bytes) {
        __half* hh = (__half*)d_ws;
        int n4 = ND / 4;
        f32_to_f16_kernel<<<(n4 + 255) / 256, 256, 0, stream>>>(h, (__half2*)hh, n4);

        // 4 edges per 8-lane group -> E/4 groups, 8 threads each.
        long long groups = (E + 3) / 4;
        long long total_threads = groups * 8;
        int grid = (int)((total_threads + 255) / 256);
        dot_sigmoid_f16_mlp_kernel<<<grid, 256, 0, stream>>>(hh, src, dst, out, E);
    } else {
        long long total_threads = (long long)E * 16;
        int grid = (int)((total_threads + 255) / 256);
        dot_sigmoid_f32_kernel<<<grid, 256, 0, stream>>>(h, src, dst, out, E);
    }
}